// Round 4
// baseline (1019.959 us; speedup 1.0000x reference)
//
#include <hip/hip_runtime.h>

#define NHEADS 8
#define DFEAT 16
#define NCLUST 200
#define NODE_FLOATS (NHEADS * DFEAT)  // 128 floats = 512 B per node

// clang-native vector type: __builtin_nontemporal_store requires a scalar or
// native vector, not HIP's float4 class.
typedef float f32x4 __attribute__((ext_vector_type(4)));
typedef float f32x2 __attribute__((ext_vector_type(2)));

// d_ws table layout (floats):
//   [0..199]   ub[s]  = inclusive_cumsum(|r|)[s] + 0.1
//   [200..399] lb[s]  = exclusive_cumsum(|r|)[s]
//   [400..599] inv[s] = 1 / (r[s]^2 + 1)
//   [600..607] weight[h] = softmax(w)[h]

__global__ void setup_tables_kernel(const float* __restrict__ w,
                                    const float* __restrict__ r,
                                    float* __restrict__ tbl) {
    if (threadIdx.x == 0 && blockIdx.x == 0) {
        float mx = w[0];
        #pragma unroll
        for (int i = 1; i < NHEADS; ++i) mx = fmaxf(mx, w[i]);
        float ex[NHEADS];
        float se = 0.f;
        #pragma unroll
        for (int i = 0; i < NHEADS; ++i) { ex[i] = expf(w[i] - mx); se += ex[i]; }
        float inv_se = 1.0f / se;
        #pragma unroll
        for (int i = 0; i < NHEADS; ++i) tbl[600 + i] = ex[i] * inv_se;

        float run = 0.f;
        for (int s = 0; s < NCLUST; ++s) {
            float rv = r[s];
            float ar = fabsf(rv);
            tbl[200 + s] = run;            // exclusive cumsum -> lower_bound
            run += ar;                     // inclusive cumsum
            tbl[s] = run + 0.1f;           // -> upper_bound
            tbl[400 + s] = 1.0f / (rv * rv + 1.0f);
        }
    }
}

// One wave (64 lanes) per edge, grid-stride over edges.
// lane layout: 8 head-groups x 8 lanes; each lane covers 2 features (float2).
// HBM-write-bound (~804 MB out): all compute hides under the store stream.
__global__ __launch_bounds__(256) void edge_score_kernel(
    const float* __restrict__ h,
    const int* __restrict__ src,
    const int* __restrict__ dst,
    const float* __restrict__ tbl,
    float* __restrict__ score,    // [E, 200]
    float* __restrict__ std_out,  // [E]
    int E) {
    const int lane = threadIdx.x & 63;
    const int waveInBlk = threadIdx.x >> 6;
    const int wavesPerBlk = blockDim.x >> 6;
    const int waveId = blockIdx.x * wavesPerBlk + waveInBlk;
    const int nWaves = gridDim.x * wavesPerBlk;

    const int head = lane >> 3;
    const int fpair = (lane & 7) << 1;
    const int elemOff = head * DFEAT + fpair;

    // loop-invariant per-lane constants
    const float wgt = tbl[600 + head];
    f32x4 ub4 = {0, 0, 0, 0}, lb4 = {0, 0, 0, 0}, iv4 = {0, 0, 0, 0};
    if (lane < NCLUST / 4) {  // lanes 0..49 own 4 clusters each
        ub4 = *reinterpret_cast<const f32x4*>(tbl + lane * 4);
        lb4 = *reinterpret_cast<const f32x4*>(tbl + 200 + lane * 4);
        iv4 = *reinterpret_cast<const f32x4*>(tbl + 400 + lane * 4);
    }

    // 1-deep index prefetch: pull src/dst one grid-stride iteration ahead.
    // nt loads: 8 MB of read-once index traffic, keep it out of L2 (the
    // 51 MB h-gather working set wants every L2 line it can get).
    int sn = 0, dn = 0;
    if (waveId < E) {
        sn = __builtin_nontemporal_load(src + waveId);
        dn = __builtin_nontemporal_load(dst + waveId);
    }

    for (int e = waveId; e < E; e += nWaves) {
        const int sn_cur = sn, dn_cur = dn;
        const int en = e + nWaves;
        if (en < E) {
            sn = __builtin_nontemporal_load(src + en);
            dn = __builtin_nontemporal_load(dst + en);
        }

        const f32x2 a = *reinterpret_cast<const f32x2*>(h + (size_t)dn_cur * NODE_FLOATS + elemOff);
        const f32x2 b = *reinterpret_cast<const f32x2*>(h + (size_t)sn_cur * NODE_FLOATS + elemOff);
        const float dx = a.x - b.x;
        const float dy = a.y - b.y;
        float ss = dx * dx + dy * dy;
        // reduce within 8-lane head group -> sum of squares for this head
        ss += __shfl_xor(ss, 1);
        ss += __shfl_xor(ss, 2);
        ss += __shfl_xor(ss, 4);
        const float n2 = sqrtf(ss);
        // dist = sum_h n2[h] * weight[h]  (reduce across the 8 head-groups)
        float c = n2 * wgt;
        c += __shfl_xor(c, 8);
        c += __shfl_xor(c, 16);
        c += __shfl_xor(c, 32);
        const float dist = c;
        // std = sqrt(mean_h (n2[h] - dist)^2)
        const float sd = n2 - dist;
        float v = sd * sd;
        v += __shfl_xor(v, 8);
        v += __shfl_xor(v, 16);
        v += __shfl_xor(v, 32);
        if (lane == 0) __builtin_nontemporal_store(sqrtf(v * 0.125f), std_out + e);
        // score row: 50 lanes x f32x4 = 200 floats, one coalesced 800 B store.
        // Non-temporal: write-once stream, keep it out of L2.
        if (lane < NCLUST / 4) {
            f32x4 o;
            o.x = (ub4.x - dist) * (dist - lb4.x) * iv4.x;
            o.y = (ub4.y - dist) * (dist - lb4.y) * iv4.y;
            o.z = (ub4.z - dist) * (dist - lb4.z) * iv4.z;
            o.w = (ub4.w - dist) * (dist - lb4.w) * iv4.w;
            __builtin_nontemporal_store(o, reinterpret_cast<f32x4*>(score + (size_t)e * NCLUST + lane * 4));
        }
    }
}

extern "C" void kernel_launch(void* const* d_in, const int* in_sizes, int n_in,
                              void* d_out, int out_size, void* d_ws, size_t ws_size,
                              hipStream_t stream) {
    const float* h = (const float*)d_in[0];
    const float* w = (const float*)d_in[1];
    const float* r = (const float*)d_in[2];
    const int* src = (const int*)d_in[3];
    const int* dst = (const int*)d_in[4];
    const int E = in_sizes[3];

    float* tbl = (float*)d_ws;                            // 608 floats
    float* score = (float*)d_out;                         // [E, 200]
    float* std_out = (float*)d_out + (size_t)E * NCLUST;  // [E]

    setup_tables_kernel<<<1, 64, 0, stream>>>(w, r, tbl);

    const int block = 256;
    const int wavesPerBlk = block / 64;
    int blocks = (E + wavesPerBlk - 1) / wavesPerBlk;
    if (blocks > 2048) blocks = 2048;
    edge_score_kernel<<<blocks, block, 0, stream>>>(h, src, dst, tbl, score, std_out, E);
}